// Round 10
// baseline (265.585 us; speedup 1.0000x reference)
//
#include <hip/hip_runtime.h>
#include <math.h>
#include <stdint.h>

#define T_TOK 8192
#define DIM   7168
#define NE    256
#define NGRP  8
#define TOPKN 8
#define ROUTE_SCALE 2.5f

typedef __bf16 bf16x8 __attribute__((ext_vector_type(8)));
typedef __bf16 bf16x4 __attribute__((ext_vector_type(4)));
typedef float f32x16 __attribute__((ext_vector_type(16)));

static __device__ __forceinline__ void glds16(const void* g, void* l) {
  __builtin_amdgcn_global_load_lds(
      (const __attribute__((address_space(1))) uint32_t*)g,
      (__attribute__((address_space(3))) uint32_t*)l, 16, 0, 0);
}
static __device__ __forceinline__ bf16x8 ldfrag(const void* p) {
  return __builtin_bit_cast(bf16x8, *reinterpret_cast<const uint4*>(p));
}

// ---- w [E][D] f32 -> wh/wl bf16 (hi + residual-lo), natural layout ---------
__global__ __launch_bounds__(256) void w_convert(const float* __restrict__ w,
                                                 uint16_t* __restrict__ wh,
                                                 uint16_t* __restrict__ wl) {
  const int e = blockIdx.x;
#pragma unroll
  for (int p = 0; p < 4; ++p) {
    const int gp = threadIdx.x + p * 256;  // granule = 8 elems
    if (gp >= DIM / 8) continue;
    const float4 a = *reinterpret_cast<const float4*>(&w[(size_t)e * DIM + gp * 8]);
    const float4 b = *reinterpret_cast<const float4*>(&w[(size_t)e * DIM + gp * 8 + 4]);
    const float src[8] = {a.x, a.y, a.z, a.w, b.x, b.y, b.z, b.w};
    __bf16 hs[8], ls[8];
#pragma unroll
    for (int u = 0; u < 8; ++u) {
      const __bf16 h = (__bf16)src[u];
      hs[u] = h;
      ls[u] = (__bf16)(src[u] - (float)h);
    }
    *reinterpret_cast<uint4*>(&wh[(size_t)e * DIM + gp * 8]) = *reinterpret_cast<const uint4*>(hs);
    *reinterpret_cast<uint4*>(&wl[(size_t)e * DIM + gp * 8]) = *reinterpret_cast<const uint4*>(ls);
  }
}

// ---- split-bf16 3-product MFMA GEMM. Block 128x128, 4 waves (2x2), wave
// tile 64x64, BK=32, K-split NSPLIT. SINGLE-buffered 32 KB LDS + two
// __syncthreads per iter -> 4 blocks/CU (m97 recipe): other blocks' compute
// fills each block's barrier drain. Prefetch: A regs one iter ahead, B DMA
// issued right after the read-barrier. ----
template <int NSPLIT>
__global__ __launch_bounds__(256, 4) void gemm_tile(
    const float* __restrict__ x, const uint16_t* __restrict__ wh,
    const uint16_t* __restrict__ wl, float* __restrict__ partial) {
  constexpr int KH = DIM / NSPLIT;
  constexpr int NIT = KH / 32;
  __shared__ __align__(16) uint16_t As[128][64];
  __shared__ __align__(16) uint16_t Bs[128][64];

  const int tid = threadIdx.x;
  const int lane = tid & 63;
  const int l31 = lane & 31;
  const int khalf = lane >> 5;
  const int wid = tid >> 6;
  const int wm = wid >> 1, wn = wid & 1;

  const int b = blockIdx.x;
  int mblk, nblk, ks;
  if (NSPLIT == 8) {            // grid 1024: b&15 -> (nblk, ks); w-slice/XCD ~0.9MB
    nblk = b & 1; ks = (b >> 1) & 7; mblk = b >> 4;
  } else if (NSPLIT == 4) {     // grid 512
    nblk = b & 1; ks = (b >> 1) & 3; mblk = b >> 3;
  } else {                      // grid 256
    nblk = b & 1; ks = (b >> 1) & 1; mblk = (b >> 3) * 2 + ((b >> 2) & 1);
  }
  const int m0 = mblk * 128, n0 = nblk * 128, k0 = ks * KH;

  // A staging map: thread -> rows (tid>>3)+32q, f32 granule c = tid&7 (16B)
  const int r0 = tid >> 3;
  const int ac = tid & 7;
  const int aG = ac >> 1;       // bf16 16B-granule 0..3
  const int ah = ac & 1;        // 8B half within granule

  f32x16 acc[2][2];
#pragma unroll
  for (int mf = 0; mf < 2; ++mf)
#pragma unroll
    for (int nf = 0; nf < 2; ++nf)
#pragma unroll
      for (int q = 0; q < 16; ++q) acc[mf][nf][q] = 0.f;

  float4 av[4];
  auto loadA = [&](int kb) {
#pragma unroll
    for (int q = 0; q < 4; ++q)
      av[q] = *reinterpret_cast<const float4*>(
          &x[(size_t)(m0 + r0 + q * 32) * DIM + kb + ac * 4]);
  };
  auto writeA = [&]() {
#pragma unroll
    for (int q = 0; q < 4; ++q) {
      const int row = r0 + q * 32;
      const float s[4] = {av[q].x, av[q].y, av[q].z, av[q].w};
      __bf16 hi[4], lo[4];
#pragma unroll
      for (int u = 0; u < 4; ++u) {
        hi[u] = (__bf16)s[u];
        lo[u] = (__bf16)(s[u] - (float)hi[u]);
      }
      const int p = aG ^ (row & 7);
      uint8_t* base = reinterpret_cast<uint8_t*>(&As[row][0]);
      *reinterpret_cast<uint2*>(base + p * 16 + ah * 8) =
          __builtin_bit_cast(uint2, *reinterpret_cast<bf16x4*>(hi));
      *reinterpret_cast<uint2*>(base + (p ^ 4) * 16 + ah * 8) =
          __builtin_bit_cast(uint2, *reinterpret_cast<bf16x4*>(lo));
    }
  };
  // B stage via DMA: LDS granule g (row=g>>3, pos=g&7) <- logical granule
  // G = (g&7)^(row&7); G<4 from wh, else wl. Lane-contiguous LDS dest.
  auto stageB = [&](int kb) {
#pragma unroll
    for (int h = 0; h < 4; ++h) {
      const int g = tid + h * 256;        // 0..1023
      const int row = g >> 3;
      const int G = (g & 7) ^ (row & 7);
      const uint16_t* src = (G < 4)
          ? wh + (size_t)(n0 + row) * DIM + kb + (G & 3) * 8
          : wl + (size_t)(n0 + row) * DIM + kb + (G & 3) * 8;
      glds16(src, &Bs[0][0] + (size_t)g * 8);
    }
  };
  auto compute = [&]() {
#pragma unroll
    for (int kk = 0; kk < 2; ++kk) {
      const int G = kk * 2 + khalf;       // 0..3
      bf16x8 fBh[2], fBl[2], fAh[2], fAl[2];
#pragma unroll
      for (int nf = 0; nf < 2; ++nf) {
        const int brow = wn * 64 + nf * 32 + l31;
        const int pb = G ^ (brow & 7);
        fBh[nf] = ldfrag(&Bs[brow][pb * 8]);
        fBl[nf] = ldfrag(&Bs[brow][(pb ^ 4) * 8]);
      }
#pragma unroll
      for (int mf = 0; mf < 2; ++mf) {
        const int arow = wm * 64 + mf * 32 + l31;
        const int pa = G ^ (arow & 7);
        fAh[mf] = ldfrag(&As[arow][pa * 8]);
        fAl[mf] = ldfrag(&As[arow][(pa ^ 4) * 8]);
      }
#pragma unroll
      for (int mf = 0; mf < 2; ++mf)
#pragma unroll
        for (int nf = 0; nf < 2; ++nf) {
          acc[mf][nf] = __builtin_amdgcn_mfma_f32_32x32x16_bf16(fAh[mf], fBh[nf], acc[mf][nf], 0, 0, 0);
          acc[mf][nf] = __builtin_amdgcn_mfma_f32_32x32x16_bf16(fAl[mf], fBh[nf], acc[mf][nf], 0, 0, 0);
          acc[mf][nf] = __builtin_amdgcn_mfma_f32_32x32x16_bf16(fAh[mf], fBl[nf], acc[mf][nf], 0, 0, 0);
        }
    }
  };

  // prologue: stage iter 0; issue A(1) loads
  loadA(k0);
  stageB(k0);
  writeA();                       // compiler waits on av only
  if (NIT > 1) loadA(k0 + 32);    // A(1) in flight across the barrier
  __syncthreads();

  for (int it = 0; it < NIT; ++it) {
    compute();
    __syncthreads();              // all reads of As/Bs done
    if (it + 1 < NIT) {
      stageB(k0 + (it + 1) * 32); // DMA next tile into same buffer
      writeA();                   // av holds x tile it+1
      if (it + 2 < NIT) loadA(k0 + (it + 2) * 32);
      __syncthreads();            // drains DMA + ds_writes (covered by other blocks)
    }
  }

  float* pout = partial + (size_t)ks * T_TOK * NE;
#pragma unroll
  for (int mf = 0; mf < 2; ++mf)
#pragma unroll
    for (int nf = 0; nf < 2; ++nf) {
      const int e = n0 + wn * 64 + nf * 32 + l31;
#pragma unroll
      for (int q = 0; q < 16; ++q) {
        const int row = wm * 64 + mf * 32 + (q & 3) + 8 * (q >> 2) + 4 * khalf;
        pout[(size_t)(m0 + row) * NE + e] = acc[mf][nf][q];
      }
    }
}

// ---- combine partials -> scores = sigmoid(sum)+bias; per-group top-2 sums.
// One lane owns one full group of one token. 32 tokens/block. ----
__global__ __launch_bounds__(256) void combine_gs(
    const float* __restrict__ partial, const float* __restrict__ bias,
    float* __restrict__ scores, float* __restrict__ gs, int nsplit) {
  const int tid = threadIdx.x;
  const int tok = blockIdx.x * 32 + (tid >> 3);
  const int g = tid & 7;
  const size_t rowo = (size_t)tok * NE + g * 32;
  const float NEG_INF = -__builtin_inff();
  float v1 = NEG_INF, v2 = NEG_INF;
#pragma unroll
  for (int c = 0; c < 8; ++c) {
    float4 v = *reinterpret_cast<const float4*>(partial + rowo + c * 4);
    for (int s2 = 1; s2 < nsplit; ++s2) {
      const float4 u = *reinterpret_cast<const float4*>(
          partial + (size_t)s2 * T_TOK * NE + rowo + c * 4);
      v.x += u.x; v.y += u.y; v.z += u.z; v.w += u.w;
    }
    const float4 bv = *reinterpret_cast<const float4*>(bias + g * 32 + c * 4);
    float4 o;
    o.x = 1.f / (1.f + expf(-v.x)) + bv.x;
    o.y = 1.f / (1.f + expf(-v.y)) + bv.y;
    o.z = 1.f / (1.f + expf(-v.z)) + bv.z;
    o.w = 1.f / (1.f + expf(-v.w)) + bv.w;
    const float sv[4] = {o.x, o.y, o.z, o.w};
#pragma unroll
    for (int u = 0; u < 4; ++u) {
      v2 = fmaxf(v2, fminf(v1, sv[u]));
      v1 = fmaxf(v1, sv[u]);
    }
    *reinterpret_cast<float4*>(scores + rowo + c * 4) = o;
  }
  gs[tok * 8 + g] = v1 + v2;
}

// ---- top-4 groups + top-8 experts; exact round-3 serial semantics; the 4
// selected groups' 128 scores cached in registers (fully static indexing). --
__global__ __launch_bounds__(64) void select_topk2(
    const float* __restrict__ scores, const float* __restrict__ gs,
    float* __restrict__ out) {
  const int t = blockIdx.x * 64 + threadIdx.x;
  const float* s = scores + (size_t)t * NE;
  const float NEG_INF = -__builtin_inff();

  float g8[8];
#pragma unroll
  for (int g = 0; g < 8; ++g) g8[g] = gs[t * 8 + g];

  unsigned selmask = 0;
  for (int r = 0; r < 4; ++r) {
    float best = NEG_INF;
    int bg = 0;
#pragma unroll
    for (int g = 0; g < 8; ++g)
      if (!((selmask >> g) & 1u) && g8[g] > best) { best = g8[g]; bg = g; }
    selmask |= (1u << bg);
  }

  unsigned mrem = selmask;
  const int sel0 = __ffs(mrem) - 1; mrem &= mrem - 1;
  const int sel1 = __ffs(mrem) - 1; mrem &= mrem - 1;
  const int sel2 = __ffs(mrem) - 1; mrem &= mrem - 1;
  const int sel3 = __ffs(mrem) - 1;
  const int gz = __ffs(~selmask & 0xffu) - 1;

  float ca[4][32];
#pragma unroll
  for (int c = 0; c < 8; ++c) {
    const float4 u0 = *reinterpret_cast<const float4*>(&s[sel0 * 32 + c * 4]);
    const float4 u1 = *reinterpret_cast<const float4*>(&s[sel1 * 32 + c * 4]);
    const float4 u2 = *reinterpret_cast<const float4*>(&s[sel2 * 32 + c * 4]);
    const float4 u3 = *reinterpret_cast<const float4*>(&s[sel3 * 32 + c * 4]);
    ca[0][c * 4 + 0] = u0.x; ca[0][c * 4 + 1] = u0.y; ca[0][c * 4 + 2] = u0.z; ca[0][c * 4 + 3] = u0.w;
    ca[1][c * 4 + 0] = u1.x; ca[1][c * 4 + 1] = u1.y; ca[1][c * 4 + 2] = u1.z; ca[1][c * 4 + 3] = u1.w;
    ca[2][c * 4 + 0] = u2.x; ca[2][c * 4 + 1] = u2.y; ca[2][c * 4 + 2] = u2.z; ca[2][c * 4 + 3] = u2.w;
    ca[3][c * 4 + 0] = u3.x; ca[3][c * 4 + 1] = u3.y; ca[3][c * 4 + 2] = u3.z; ca[3][c * 4 + 3] = u3.w;
  }

  uint32_t ex[4] = {0, 0, 0, 0};
  int zcnt = 0;
  for (int r = 0; r < TOPKN; ++r) {
    float best = NEG_INF;
    int bq = 0, bi = 0;
#pragma unroll
    for (int q = 0; q < 4; ++q)
#pragma unroll
      for (int i = 0; i < 32; ++i) {
        const float v = ca[q][i];
        if (!((ex[q] >> i) & 1u) && v > best) { best = v; bq = q; bi = i; }
      }
    const int bg = (bq == 0) ? sel0 : (bq == 1) ? sel1 : (bq == 2) ? sel2 : sel3;
    const int be = bg * 32 + bi;
    const int ze = gz * 32 + zcnt;
    const bool takeReal = (best > 0.0f) || (best == 0.0f && be < ze);
    if (takeReal) {
#pragma unroll
      for (int q = 0; q < 4; ++q)
        if (q == bq) ex[q] |= 1u << bi;
      out[(size_t)t * TOPKN + r] = best * ROUTE_SCALE;
      out[(size_t)T_TOK * TOPKN + (size_t)t * TOPKN + r] = (float)be;
    } else {
      out[(size_t)t * TOPKN + r] = s[ze] * ROUTE_SCALE;
      out[(size_t)T_TOK * TOPKN + (size_t)t * TOPKN + r] = (float)ze;
      ++zcnt;
    }
  }
}

extern "C" void kernel_launch(void* const* d_in, const int* in_sizes, int n_in,
                              void* d_out, int out_size, void* d_ws, size_t ws_size,
                              hipStream_t stream) {
  const float* x = (const float*)d_in[0];
  const float* w = (const float*)d_in[1];
  const float* bias = (const float*)d_in[2];
  float* out = (float*)d_out;

  const size_t SC = (size_t)T_TOK * NE;
  const size_t WBYTES = (size_t)NE * DIM * 2;
  const size_t need8 = (8 * SC + (size_t)T_TOK * 8) * 4 + 2 * WBYTES;
  const size_t need4 = (4 * SC + (size_t)T_TOK * 8) * 4 + 2 * WBYTES;
  const int nsplit = (ws_size >= need8) ? 8 : (ws_size >= need4) ? 4 : 2;

  float* part = (float*)d_ws;
  float* gsbuf = part + (size_t)nsplit * SC;
  uint16_t* whp = (uint16_t*)(gsbuf + (size_t)T_TOK * 8);
  uint16_t* wlp = whp + (size_t)NE * DIM;
  float* scores = part;

  w_convert<<<NE, 256, 0, stream>>>(w, whp, wlp);
  if (nsplit == 8)
    gemm_tile<8><<<1024, 256, 0, stream>>>(x, whp, wlp, part);
  else if (nsplit == 4)
    gemm_tile<4><<<512, 256, 0, stream>>>(x, whp, wlp, part);
  else
    gemm_tile<2><<<256, 256, 0, stream>>>(x, whp, wlp, part);
  combine_gs<<<T_TOK / 32, 256, 0, stream>>>(part, bias, scores, gsbuf, nsplit);
  select_topk2<<<T_TOK / 64, 64, 0, stream>>>(scores, gsbuf, out);
}

// Round 11
// 175.987 us; speedup vs baseline: 1.5091x; 1.5091x over previous
//
#include <hip/hip_runtime.h>
#include <math.h>
#include <stdint.h>

#define T_TOK 8192
#define DIM   7168
#define NE    256
#define NGRP  8
#define TOPKN 8
#define ROUTE_SCALE 2.5f

typedef __bf16 bf16x8 __attribute__((ext_vector_type(8)));
typedef float f32x16 __attribute__((ext_vector_type(16)));

static __device__ __forceinline__ void glds16(const void* g, void* l) {
  __builtin_amdgcn_global_load_lds(
      (const __attribute__((address_space(1))) uint32_t*)g,
      (__attribute__((address_space(3))) uint32_t*)l, 16, 0, 0);
}
static __device__ __forceinline__ bf16x8 ldfrag(const void* p) {
  return __builtin_bit_cast(bf16x8, *reinterpret_cast<const uint4*>(p));
}

// ---- w [E][D] f32 -> wh/wl bf16 (hi + residual-lo), natural layout ---------
__global__ __launch_bounds__(256) void w_convert(const float* __restrict__ w,
                                                 uint16_t* __restrict__ wh,
                                                 uint16_t* __restrict__ wl) {
  const int e = blockIdx.x;
#pragma unroll
  for (int p = 0; p < 4; ++p) {
    const int gp = threadIdx.x + p * 256;  // granule = 8 elems
    if (gp >= DIM / 8) continue;
    const float4 a = *reinterpret_cast<const float4*>(&w[(size_t)e * DIM + gp * 8]);
    const float4 b = *reinterpret_cast<const float4*>(&w[(size_t)e * DIM + gp * 8 + 4]);
    const float src[8] = {a.x, a.y, a.z, a.w, b.x, b.y, b.z, b.w};
    __bf16 hs[8], ls[8];
#pragma unroll
    for (int u = 0; u < 8; ++u) {
      const __bf16 h = (__bf16)src[u];
      hs[u] = h;
      ls[u] = (__bf16)(src[u] - (float)h);
    }
    *reinterpret_cast<uint4*>(&wh[(size_t)e * DIM + gp * 8]) = *reinterpret_cast<const uint4*>(hs);
    *reinterpret_cast<uint4*>(&wl[(size_t)e * DIM + gp * 8]) = *reinterpret_cast<const uint4*>(ls);
  }
}

// ---- split-bf16 3-product MFMA GEMM, 8-phase-style interleaved schedule.
// Block 256x256 (BN = all experts), BK=32, 512 thr / 8 waves (2M x 4N),
// wave tile 128x64. LDS 2buf x (A 32K + B 32K) = 128 KB, 1 block/CU.
// Per K-step: 4 phases {ds_read frags; setprio1; 12 MFMA; setprio0; barrier}.
// P0 issues next A-loads + all B-DMA (issue-early); P3 writes A (write-late)
// then the ONLY drain (vmcnt0+lgkm0) covered by ~3 phases of compute. ----
template <int NSPLIT>
__global__ __launch_bounds__(512, 1) void gemm_8p(
    const float* __restrict__ x, const uint16_t* __restrict__ wh,
    const uint16_t* __restrict__ wl, float* __restrict__ partial) {
  constexpr int KH = DIM / NSPLIT;
  constexpr int NIT = KH / 32;
  __shared__ __align__(16) uint16_t As[2][256][64];  // [buf][row][hi 0..31 | lo 32..63]
  __shared__ __align__(16) uint16_t Bs[2][256][64];

  const int tid = threadIdx.x;
  const int lane = tid & 63;
  const int l31 = lane & 31;
  const int khalf = lane >> 5;
  const int wid = tid >> 6;          // 0..7
  const int wm = wid >> 2;           // 0..1  (M half)
  const int wn = wid & 3;            // 0..3  (N quarter)

  const int b = blockIdx.x;
  const int ks = b % NSPLIT;         // b&7 = XCD id when NSPLIT=8 -> w K-slice/XCD ~0.9MB
  const int mblk = b / NSPLIT;
  const int m0 = mblk * 256, k0 = ks * KH;

  // A staging: thread -> row ar (0..255), 16-f32 half ah2
  const int ar = tid >> 1;
  const int ah2 = tid & 1;

  f32x16 acc[4][2];
#pragma unroll
  for (int mf = 0; mf < 4; ++mf)
#pragma unroll
    for (int nf = 0; nf < 2; ++nf)
#pragma unroll
      for (int q = 0; q < 16; ++q) acc[mf][nf][q] = 0.f;

  float4 av[4];
  auto loadA = [&](int kb) {
#pragma unroll
    for (int q = 0; q < 4; ++q)
      av[q] = *reinterpret_cast<const float4*>(
          &x[(size_t)(m0 + ar) * DIM + kb + ah2 * 16 + q * 4]);
  };
  auto writeA = [&](int buf) {
#pragma unroll
    for (int g2 = 0; g2 < 2; ++g2) {   // two 8-f32 granules
      __bf16 h8[8], l8[8];
#pragma unroll
      for (int u = 0; u < 8; ++u) {
        const float fv = reinterpret_cast<const float*>(av)[g2 * 8 + u];
        const __bf16 h = (__bf16)fv;
        h8[u] = h;
        l8[u] = (__bf16)(fv - (float)h);
      }
      const int g = ah2 * 2 + g2;      // hi granule 0..3
      const int p = g ^ (ar & 7);
      *reinterpret_cast<uint4*>(&As[buf][ar][p * 8]) = *reinterpret_cast<const uint4*>(h8);
      *reinterpret_cast<uint4*>(&As[buf][ar][(p ^ 4) * 8]) = *reinterpret_cast<const uint4*>(l8);
    }
  };
  // B via DMA: LDS granule g (row=g>>3, pos=g&7) <- logical G=(g&7)^(row&7);
  // G<4 -> wh granule G, else wl granule G-4. Lane-contiguous LDS dest.
  auto stageB = [&](int buf, int kb) {
#pragma unroll
    for (int h = 0; h < 4; ++h) {
      const int g = tid + h * 512;     // 0..2047
      const int row = g >> 3;
      const int G = (g & 7) ^ (row & 7);
      const uint16_t* src = (G < 4)
          ? wh + (size_t)row * DIM + kb + (G & 3) * 8
          : wl + (size_t)row * DIM + kb + (G & 3) * 8;
      glds16(src, &Bs[buf][0][0] + (size_t)g * 8);
    }
  };
  // one phase: frags for (mh,kk) -> 12 MFMA
  auto phase = [&](int buf, int mh, int kk) {
    const int G = kk * 2 + khalf;
    bf16x8 fBh[2], fBl[2], fAh[2], fAl[2];
#pragma unroll
    for (int nf = 0; nf < 2; ++nf) {
      const int brow = wn * 64 + nf * 32 + l31;
      const int pb = G ^ (brow & 7);
      fBh[nf] = ldfrag(&Bs[buf][brow][pb * 8]);
      fBl[nf] = ldfrag(&Bs[buf][brow][(pb ^ 4) * 8]);
    }
#pragma unroll
    for (int mi = 0; mi < 2; ++mi) {
      const int arow = wm * 128 + (mh * 2 + mi) * 32 + l31;
      const int pa = G ^ (arow & 7);
      fAh[mi] = ldfrag(&As[buf][arow][pa * 8]);
      fAl[mi] = ldfrag(&As[buf][arow][(pa ^ 4) * 8]);
    }
    __builtin_amdgcn_s_setprio(1);
#pragma unroll
    for (int mi = 0; mi < 2; ++mi) {
      const int mf = mh * 2 + mi;
#pragma unroll
      for (int nf = 0; nf < 2; ++nf) {
        acc[mf][nf] = __builtin_amdgcn_mfma_f32_32x32x16_bf16(fAh[mi], fBh[nf], acc[mf][nf], 0, 0, 0);
        acc[mf][nf] = __builtin_amdgcn_mfma_f32_32x32x16_bf16(fAl[mi], fBh[nf], acc[mf][nf], 0, 0, 0);
        acc[mf][nf] = __builtin_amdgcn_mfma_f32_32x32x16_bf16(fAh[mi], fBl[nf], acc[mf][nf], 0, 0, 0);
      }
    }
    __builtin_amdgcn_s_setprio(0);
  };

  // ---- prologue: fill buffer 0 ----
  loadA(k0);
  stageB(0, k0);
  writeA(0);                                      // compiler waits av
  asm volatile("s_waitcnt vmcnt(0) lgkmcnt(0)" ::: "memory");
  __builtin_amdgcn_sched_barrier(0);
  __builtin_amdgcn_s_barrier();

  for (int it = 0; it < NIT; ++it) {
    const int cur = it & 1;
    const int nxt = cur ^ 1;
    const bool more = (it + 1) < NIT;
    // P0: issue-early staging for nxt, then compute quadrant
    if (more) {
      loadA(k0 + (it + 1) * 32);
      stageB(nxt, k0 + (it + 1) * 32);
    }
    phase(cur, 0, 0);
    __builtin_amdgcn_s_barrier();
    // P1
    phase(cur, 0, 1);
    __builtin_amdgcn_s_barrier();
    // P2
    phase(cur, 1, 0);
    __builtin_amdgcn_s_barrier();
    // P3: compute, then write-late A, then the only drain of the K-step
    phase(cur, 1, 1);
    if (more) {
      writeA(nxt);                                // compiler waits av
      asm volatile("s_waitcnt vmcnt(0) lgkmcnt(0)" ::: "memory");
      __builtin_amdgcn_sched_barrier(0);
      __builtin_amdgcn_s_barrier();
    }
  }

  float* pout = partial + (size_t)ks * T_TOK * NE;
#pragma unroll
  for (int mf = 0; mf < 4; ++mf)
#pragma unroll
    for (int nf = 0; nf < 2; ++nf) {
      const int e = wn * 64 + nf * 32 + l31;
#pragma unroll
      for (int q = 0; q < 16; ++q) {
        const int row = wm * 128 + mf * 32 + (q & 3) + 8 * (q >> 2) + 4 * khalf;
        pout[(size_t)(m0 + row) * NE + e] = acc[mf][nf][q];
      }
    }
}

// ---- split-K reduce + sigmoid + bias (pure elementwise, massively parallel)
__global__ __launch_bounds__(256) void reduce_sb(
    const float* __restrict__ partial, const float* __restrict__ bias,
    float* __restrict__ scores, int nsplit) {
  const size_t i4 = (size_t)blockIdx.x * 256 + threadIdx.x;  // float4 chunk id
  float4 v = reinterpret_cast<const float4*>(partial)[i4];
#pragma unroll 8
  for (int s2 = 1; s2 < nsplit; ++s2) {
    const float4 u = reinterpret_cast<const float4*>(
        partial + (size_t)s2 * T_TOK * NE)[i4];
    v.x += u.x; v.y += u.y; v.z += u.z; v.w += u.w;
  }
  const int e = (int)((i4 * 4) & (NE - 1));
  const float4 bv = *reinterpret_cast<const float4*>(&bias[e]);
  float4 o;
  o.x = 1.f / (1.f + expf(-v.x)) + bv.x;
  o.y = 1.f / (1.f + expf(-v.y)) + bv.y;
  o.z = 1.f / (1.f + expf(-v.z)) + bv.z;
  o.w = 1.f / (1.f + expf(-v.w)) + bv.w;
  reinterpret_cast<float4*>(scores)[i4] = o;
}

// ---- group scores + top-4 groups + top-8 experts, exact serial reference
// semantics (strict >, lowest index ties; 0.0-candidates from lowest
// unselected group ascending). gs computed in-kernel. 1 thread/token. ----
__global__ __launch_bounds__(64) void select_topk3(
    const float* __restrict__ scores, float* __restrict__ out) {
  const int t = blockIdx.x * 64 + threadIdx.x;
  const float* s = scores + (size_t)t * NE;
  const float NEG_INF = -__builtin_inff();

  // group scores: value-multiset top-2 sum (== index-exclusion top-2)
  float g8[8];
#pragma unroll
  for (int g = 0; g < 8; ++g) {
    float v1 = NEG_INF, v2 = NEG_INF;
#pragma unroll
    for (int c = 0; c < 8; ++c) {
      const float4 u = *reinterpret_cast<const float4*>(&s[g * 32 + c * 4]);
      const float sv[4] = {u.x, u.y, u.z, u.w};
#pragma unroll
      for (int k = 0; k < 4; ++k) {
        v2 = fmaxf(v2, fminf(v1, sv[k]));
        v1 = fmaxf(v1, sv[k]);
      }
    }
    g8[g] = v1 + v2;
  }

  unsigned selmask = 0;
  for (int r = 0; r < 4; ++r) {
    float best = NEG_INF;
    int bg = 0;
#pragma unroll
    for (int g = 0; g < 8; ++g)
      if (!((selmask >> g) & 1u) && g8[g] > best) { best = g8[g]; bg = g; }
    selmask |= (1u << bg);
  }

  unsigned mrem = selmask;
  const int sel0 = __ffs(mrem) - 1; mrem &= mrem - 1;
  const int sel1 = __ffs(mrem) - 1; mrem &= mrem - 1;
  const int sel2 = __ffs(mrem) - 1; mrem &= mrem - 1;
  const int sel3 = __ffs(mrem) - 1;
  const int gz = __ffs(~selmask & 0xffu) - 1;

  float ca[4][32];
#pragma unroll
  for (int c = 0; c < 8; ++c) {
    const float4 u0 = *reinterpret_cast<const float4*>(&s[sel0 * 32 + c * 4]);
    const float4 u1 = *reinterpret_cast<const float4*>(&s[sel1 * 32 + c * 4]);
    const float4 u2 = *reinterpret_cast<const float4*>(&s[sel2 * 32 + c * 4]);
    const float4 u3 = *reinterpret_cast<const float4*>(&s[sel3 * 32 + c * 4]);
    ca[0][c * 4 + 0] = u0.x; ca[0][c * 4 + 1] = u0.y; ca[0][c * 4 + 2] = u0.z; ca[0][c * 4 + 3] = u0.w;
    ca[1][c * 4 + 0] = u1.x; ca[1][c * 4 + 1] = u1.y; ca[1][c * 4 + 2] = u1.z; ca[1][c * 4 + 3] = u1.w;
    ca[2][c * 4 + 0] = u2.x; ca[2][c * 4 + 1] = u2.y; ca[2][c * 4 + 2] = u2.z; ca[2][c * 4 + 3] = u2.w;
    ca[3][c * 4 + 0] = u3.x; ca[3][c * 4 + 1] = u3.y; ca[3][c * 4 + 2] = u3.z; ca[3][c * 4 + 3] = u3.w;
  }

  uint32_t ex[4] = {0, 0, 0, 0};
  int zcnt = 0;
  for (int r = 0; r < TOPKN; ++r) {
    float best = NEG_INF;
    int bq = 0, bi = 0;
#pragma unroll
    for (int q = 0; q < 4; ++q)
#pragma unroll
      for (int i = 0; i < 32; ++i) {
        const float v = ca[q][i];
        if (!((ex[q] >> i) & 1u) && v > best) { best = v; bq = q; bi = i; }
      }
    const int bg = (bq == 0) ? sel0 : (bq == 1) ? sel1 : (bq == 2) ? sel2 : sel3;
    const int be = bg * 32 + bi;
    const int ze = gz * 32 + zcnt;
    const bool takeReal = (best > 0.0f) || (best == 0.0f && be < ze);
    if (takeReal) {
#pragma unroll
      for (int q = 0; q < 4; ++q)
        if (q == bq) ex[q] |= 1u << bi;
      out[(size_t)t * TOPKN + r] = best * ROUTE_SCALE;
      out[(size_t)T_TOK * TOPKN + (size_t)t * TOPKN + r] = (float)be;
    } else {
      out[(size_t)t * TOPKN + r] = s[ze] * ROUTE_SCALE;
      out[(size_t)T_TOK * TOPKN + (size_t)t * TOPKN + r] = (float)ze;
      ++zcnt;
    }
  }
}

extern "C" void kernel_launch(void* const* d_in, const int* in_sizes, int n_in,
                              void* d_out, int out_size, void* d_ws, size_t ws_size,
                              hipStream_t stream) {
  const float* x = (const float*)d_in[0];
  const float* w = (const float*)d_in[1];
  const float* bias = (const float*)d_in[2];
  float* out = (float*)d_out;

  const size_t SC = (size_t)T_TOK * NE;
  const size_t WBYTES = (size_t)NE * DIM * 2;
  const size_t need8 = 8 * SC * 4 + 2 * WBYTES;
  const size_t need4 = 4 * SC * 4 + 2 * WBYTES;
  const int nsplit = (ws_size >= need8) ? 8 : (ws_size >= need4) ? 4 : 2;

  float* part = (float*)d_ws;
  uint16_t* whp = (uint16_t*)(part + (size_t)nsplit * SC);
  uint16_t* wlp = whp + (size_t)NE * DIM;
  float* scores = part;  // reduce overlays partial[0] (same-thread RAW only)

  w_convert<<<NE, 256, 0, stream>>>(w, whp, wlp);
  if (nsplit == 8)
    gemm_8p<8><<<256, 512, 0, stream>>>(x, whp, wlp, part);
  else if (nsplit == 4)
    gemm_8p<4><<<128, 512, 0, stream>>>(x, whp, wlp, part);
  else
    gemm_8p<2><<<64, 512, 0, stream>>>(x, whp, wlp, part);
  reduce_sb<<<(int)(SC / 4 / 256), 256, 0, stream>>>(part, bias, scores, nsplit);
  select_topk3<<<T_TOK / 64, 64, 0, stream>>>(scores, out);
}